// Round 3
// baseline (4598.476 us; speedup 1.0000x reference)
//
#include <hip/hip_runtime.h>

// ---------------- types / helpers ----------------
typedef short bhalf8 __attribute__((ext_vector_type(8)));   // 8 bf16 in 4 VGPRs
typedef float f32x4  __attribute__((ext_vector_type(4)));

__device__ __forceinline__ unsigned short f2bf(float f) {
    unsigned int u = __builtin_bit_cast(unsigned int, f);
    u = (u + 0x7fffu + ((u >> 16) & 1u)) >> 16;   // RNE
    return (unsigned short)u;
}
__device__ __forceinline__ float bf2f(unsigned short h) {
    unsigned int u = ((unsigned int)h) << 16;
    return __builtin_bit_cast(float, u);
}

// L2-bypass 16B load (sc0 sc1 -> reads the agent coherence point / MALL).
// hbuf is ONLY ever accessed with bypass ops, so no cache level ever holds a
// stale copy and no buffer_inv is needed at the barrier.
__device__ __forceinline__ bhalf8 ldg16_bypass(const unsigned short* p) {
    bhalf8 r;
    asm volatile("global_load_dwordx4 %0, %1, off sc0 sc1"
                 : "=v"(r) : "v"(p));
    return r;
}

// counted vmcnt wait; sched_barrier stops hipcc hoisting ops past it (rule #18)
#define VWAIT(N)                                                     \
    do {                                                             \
        asm volatile("s_waitcnt vmcnt(" #N ")" ::: "memory");        \
        __builtin_amdgcn_sched_barrier(0);                           \
    } while (0)

#define SEQ   512
#define BATCH 64
#define HID   1024
#define EMBD  1024
#define VOCAB 32000
#define N3H   3072
#define NBLK  64
#define FLAGSTRIDE 32   // ints; 128B line per flag

// ---------------- fp32 -> bf16 convert (4 elems/thread) ----------------
__global__ void k_cvt4(const float4* __restrict__ in, ushort4* __restrict__ out, int n4) {
    int i = blockIdx.x * blockDim.x + threadIdx.x;
    if (i < n4) {
        float4 v = in[i];
        ushort4 o;
        o.x = f2bf(v.x); o.y = f2bf(v.y); o.z = f2bf(v.z); o.w = f2bf(v.w);
        out[i] = o;
    }
}

// ---------------- gi GEMM: (32768 x 1024) gathered-A  @  W_ih^T -> bf16 ----------------
__global__ __launch_bounds__(256)
void k_gi(const int* __restrict__ tok, const unsigned short* __restrict__ embb,
          const unsigned short* __restrict__ wih, unsigned short* __restrict__ gi) {
    int nb = blockIdx.x;            // 0..47
    int mb = blockIdx.y;            // 0..127
    int w    = threadIdx.x >> 6;
    int lane = threadIdx.x & 63;
    int q = lane >> 4, l = lane & 15;
    int m0 = mb * 256 + w * 16;
    int n0 = nb * 64;

    const unsigned short* ap[4];
#pragma unroll
    for (int i = 0; i < 4; ++i)
        ap[i] = embb + (size_t)tok[m0 + 64 * i + l] * EMBD + q * 8;

    const unsigned short* bp[4];
#pragma unroll
    for (int j = 0; j < 4; ++j)
        bp[j] = wih + (size_t)(n0 + 16 * j + l) * EMBD + q * 8;

    f32x4 acc[4][4];
#pragma unroll
    for (int i = 0; i < 4; ++i)
#pragma unroll
        for (int j = 0; j < 4; ++j)
            acc[i][j] = (f32x4){0.f, 0.f, 0.f, 0.f};

#pragma unroll 2
    for (int kk = 0; kk < 32; ++kk) {
        int ko = kk * 32;
        bhalf8 bv[4], av[4];
#pragma unroll
        for (int j = 0; j < 4; ++j) bv[j] = *(const bhalf8*)(bp[j] + ko);
#pragma unroll
        for (int i = 0; i < 4; ++i) av[i] = *(const bhalf8*)(ap[i] + ko);
#pragma unroll
        for (int i = 0; i < 4; ++i)
#pragma unroll
            for (int j = 0; j < 4; ++j)
                acc[i][j] = __builtin_amdgcn_mfma_f32_16x16x32_bf16(av[i], bv[j], acc[i][j], 0, 0, 0);
    }
#pragma unroll
    for (int i = 0; i < 4; ++i)
#pragma unroll
        for (int r = 0; r < 4; ++r) {
            size_t mrow = (size_t)(m0 + 64 * i + q * 4 + r) * N3H + n0;
            gi[mrow +  0 + l] = f2bf(acc[i][0][r]);
            gi[mrow + 16 + l] = f2bf(acc[i][1][r]);
            gi[mrow + 32 + l] = f2bf(acc[i][2][r]);
            gi[mrow + 48 + l] = f2bf(acc[i][3][r]);
        }
}

// ---------------- flag barrier: no RMW, no acquire-inv ----------------
// Arrive: __syncthreads drains vmcnt (h write-through stores are then at the
// agent coherence point), then thread 0 does ONE relaxed agent STORE of the
// epoch to this block's private flag line. Detect: wave 0's 64 lanes each
// poll one block's flag in parallel; done when __all(v >= e).
// Correct because hbuf is only ever accessed with L2-bypass (sc0 sc1) ops.
__device__ __forceinline__ void gbar(int* flags, int e) {
    __syncthreads();   // vmcnt(0): this block's h stores are agent-visible
    if (threadIdx.x == 0)
        __hip_atomic_store(flags + (size_t)blockIdx.x * FLAGSTRIDE, e,
                           __ATOMIC_RELAXED, __HIP_MEMORY_SCOPE_AGENT);
    if (threadIdx.x < 64) {
        for (;;) {
            int v = __hip_atomic_load(flags + (size_t)threadIdx.x * FLAGSTRIDE,
                                      __ATOMIC_RELAXED, __HIP_MEMORY_SCOPE_AGENT);
            if (__all(v >= e)) break;
            __builtin_amdgcn_s_sleep(1);
        }
    }
    __syncthreads();
}

// ---------------- persistent recurrence ----------------
// 64 blocks = 64 unit-groups; block = 256 thr (4 waves = 4 batch-quarters).
// Per-step VMEM stream is pinned with volatile asm in a FIXED order so counted
// vmcnt waits are exact (in-order retirement):
//   h loads a,b,c,d (8 each, 32 total) -> gi loads (12) -> out stores (4)
//   a ready @ vmcnt<=40, b<=32, c<=24, d<=16, gi<=4 (only out-stores pending).
__global__ __launch_bounds__(256, 1)
void k_rec(const float* __restrict__ W_hh,
           const unsigned short* __restrict__ gib,
           const float* __restrict__ bih, const float* __restrict__ bhh,
           const float* __restrict__ hidden,
           float* __restrict__ out,
           unsigned short* hbuf,          // bf16 [2][64*1024], bypass-only
           int* flags) {                  // [NBLK*FLAGSTRIDE], zeroed
    __shared__ unsigned short sh[32768];  // 64 KB: gates r,z for this unit group

    const int tid  = threadIdx.x;
    const int w    = tid >> 6;            // batch quarter 0..3
    const int lane = tid & 63;
    const int q = lane >> 4, l = lane & 15;
    const int G  = blockIdx.x;            // unit group 0..63
    const int m0 = w * 16;
    const int u0 = G * 16 + l;

    // ---- prologue: r,z gate fragments -> LDS ----
    for (int i = 0; i < 16; ++i) {
        int c  = i * 256 + tid;           // 0..4095
        int g  = c >> 11;                 // 0..1
        int kk = (c >> 6) & 31;
        int ln = c & 63;
        int uu = ln & 15, qq = ln >> 4;
        const float* src = W_hh + (size_t)(g * 1024 + G * 16 + uu) * 1024 + kk * 32 + qq * 8;
        float4 f0 = *(const float4*)src;
        float4 f1 = *(const float4*)(src + 4);
        ushort4 o0, o1;
        o0.x = f2bf(f0.x); o0.y = f2bf(f0.y); o0.z = f2bf(f0.z); o0.w = f2bf(f0.w);
        o1.x = f2bf(f1.x); o1.y = f2bf(f1.y); o1.z = f2bf(f1.z); o1.w = f2bf(f1.w);
        *(ushort4*)&sh[c * 8]     = o0;
        *(ushort4*)&sh[c * 8 + 4] = o1;
    }

    // ---- n-gate fragments in registers ----
    bhalf8 bn[32];
#pragma unroll
    for (int kk = 0; kk < 32; ++kk) {
        const float* src = W_hh + (size_t)(2048 + u0) * 1024 + kk * 32 + q * 8;
        float4 f0 = *(const float4*)src;
        float4 f1 = *(const float4*)(src + 4);
        bhalf8 v;
        v[0] = (short)f2bf(f0.x); v[1] = (short)f2bf(f0.y);
        v[2] = (short)f2bf(f0.z); v[3] = (short)f2bf(f0.w);
        v[4] = (short)f2bf(f1.x); v[5] = (short)f2bf(f1.y);
        v[6] = (short)f2bf(f1.z); v[7] = (short)f2bf(f1.w);
        bn[kk] = v;
    }

    // ---- h0 init + biases (hbuf written write-through, bypass-only) ----
    float hp[4];
#pragma unroll
    for (int r = 0; r < 4; ++r) {
        int b = m0 + q * 4 + r;
        float hv = hidden[(size_t)b * HID + u0];
        hp[r] = hv;
        __hip_atomic_store(hbuf + (size_t)b * HID + u0, f2bf(hv),
                           __ATOMIC_RELAXED, __HIP_MEMORY_SCOPE_AGENT);
    }
    float bir = bih[u0], biz = bih[HID + u0], bin = bih[2 * HID + u0];
    float bhr = bhh[u0], bhz = bhh[HID + u0], bhn = bhh[2 * HID + u0];

    // ---- gi for t=0 (b_ih folded in) ----
    float i_r[4], i_z[4], i_n[4];
#pragma unroll
    for (int r = 0; r < 4; ++r) {
        const unsigned short* gp = gib + (size_t)(m0 + q * 4 + r) * N3H + u0;
        i_r[r] = bf2f(gp[0])       + bir;
        i_z[r] = bf2f(gp[HID])     + biz;
        i_n[r] = bf2f(gp[2 * HID]) + bin;
    }

    gbar(flags, 1);   // h0 visible everywhere

// h-load group: 8 bypass loads (issue only, no wait)
#define ISSUE8(AV, KB)                                                   \
    _Pragma("unroll")                                                    \
    for (int j = 0; j < 8; ++j) AV[j] = ldg16_bypass(hA + ((KB) + j) * 32);

// compute 8 k-slices consuming AV
#define COMPUTE8(AV, KB)                                                 \
    _Pragma("unroll")                                                    \
    for (int j = 0; j < 8; ++j) {                                        \
        int kk = (KB) + j;                                               \
        bhalf8 brf = *(const bhalf8*)&sh[kk * 512 + lane * 8];           \
        bhalf8 bzf = *(const bhalf8*)&sh[16384 + kk * 512 + lane * 8];   \
        ar = __builtin_amdgcn_mfma_f32_16x16x32_bf16(AV[j], brf, ar, 0, 0, 0); \
        az = __builtin_amdgcn_mfma_f32_16x16x32_bf16(AV[j], bzf, az, 0, 0, 0); \
        an = __builtin_amdgcn_mfma_f32_16x16x32_bf16(AV[j], bn[kk], an, 0, 0, 0); \
    }

    float osv[4] = {0.f, 0.f, 0.f, 0.f};   // previous step's outputs

    for (int t = 0; t < SEQ; ++t) {
        const unsigned short* hc = hbuf + (size_t)(t & 1) * (BATCH * HID);
        unsigned short*       hn = hbuf + (size_t)((t + 1) & 1) * (BATCH * HID);
        const unsigned short* hA = hc + (size_t)(m0 + l) * HID + q * 8;

        f32x4 ar = {0.f, 0.f, 0.f, 0.f}, az = ar, an = ar;

        // ---- (1) issue 32 h bypass loads, 4 groups of 8 ----
        bhalf8 ha[8], hb[8], hcv[8], hd[8];
        ISSUE8(ha,  0)
        ISSUE8(hb,  8)
        ISSUE8(hcv, 16)
        ISSUE8(hd,  24)

        // ---- (2) issue 12 gi loads for t+1 (clamped; uniform count) ----
        unsigned int pr[4], pz[4], pn[4];
        {
            const unsigned short* gt = gib +
                (size_t)((t + 1 < SEQ) ? (t + 1) : t) * (BATCH * N3H);
#pragma unroll
            for (int r = 0; r < 4; ++r) {
                const unsigned short* gp = gt + (size_t)(m0 + q * 4 + r) * N3H + u0;
                asm volatile("global_load_ushort %0, %1, off" : "=v"(pr[r]) : "v"(gp));
                asm volatile("global_load_ushort %0, %1, off" : "=v"(pz[r]) : "v"(gp + HID));
                asm volatile("global_load_ushort %0, %1, off" : "=v"(pn[r]) : "v"(gp + 2 * HID));
            }
        }

        // ---- (3) issue 4 PLAIN out stores for step t-1 (L2-ack, lazy flush).
        // t==0 stores garbage to out[0]; overwritten by the same thread at t==1.
        {
            float* ot = out + (size_t)(t ? t - 1 : 0) * (BATCH * HID);
#pragma unroll
            for (int r = 0; r < 4; ++r) {
                float* op = &ot[(size_t)(m0 + q * 4 + r) * HID + u0];
                asm volatile("global_store_dword %0, %1, off"
                             :: "v"(op), "v"(osv[r]) : "memory");
            }
        }

        // ---- (4) k-loop with exact counted waits ----
        VWAIT(40);  COMPUTE8(ha,  0)
        VWAIT(32);  COMPUTE8(hb,  8)
        VWAIT(24);  COMPUTE8(hcv, 16)
        VWAIT(16);  COMPUTE8(hd,  24)
        VWAIT(4);   // gi loads retired; only the 4 out-stores may remain

        // ---- (5) gate math + h(t+1) write-through stores ----
#pragma unroll
        for (int r = 0; r < 4; ++r) {
            int b = m0 + q * 4 + r;
            float rr = 1.f / (1.f + __expf(-(i_r[r] + ar[r] + bhr)));
            float zz = 1.f / (1.f + __expf(-(i_z[r] + az[r] + bhz)));
            float nn = tanhf(i_n[r] + rr * (an[r] + bhn));
            float hv = (1.f - zz) * nn + zz * hp[r];
            hp[r] = hv;
            osv[r] = hv;
            if (t + 1 < SEQ)
                __hip_atomic_store(hn + (size_t)b * HID + u0, f2bf(hv),
                                   __ATOMIC_RELAXED, __HIP_MEMORY_SCOPE_AGENT);
        }

        // fold bias into next step's gi
#pragma unroll
        for (int r = 0; r < 4; ++r) {
            i_r[r] = bf2f((unsigned short)pr[r]) + bir;
            i_z[r] = bf2f((unsigned short)pz[r]) + biz;
            i_n[r] = bf2f((unsigned short)pn[r]) + bin;
        }

        if (t + 1 < SEQ) gbar(flags, t + 2);
    }

    // epilogue: final step's outputs
    {
        float* ot = out + (size_t)(SEQ - 1) * (BATCH * HID);
#pragma unroll
        for (int r = 0; r < 4; ++r)
            ot[(size_t)(m0 + q * 4 + r) * HID + u0] = osv[r];
    }
#undef ISSUE8
#undef COMPUTE8
}

// ---------------- launch ----------------
extern "C" void kernel_launch(void* const* d_in, const int* in_sizes, int n_in,
                              void* d_out, int out_size, void* d_ws, size_t ws_size,
                              hipStream_t stream) {
    (void)in_sizes; (void)n_in; (void)out_size;
    const int*   input  = (const int*)  d_in[0];
    const float* hidden = (const float*)d_in[2];
    const float* emb    = (const float*)d_in[3];
    const float* W_ih   = (const float*)d_in[4];
    const float* W_hh   = (const float*)d_in[5];
    const float* b_ih   = (const float*)d_in[6];
    const float* b_hh   = (const float*)d_in[7];
    float* out = (float*)d_out;

    // workspace layout (bytes)
    const size_t EMB_BF  = 0;                                   // 65,536,000
    const size_t WIH_BF  = EMB_BF + (size_t)VOCAB * EMBD * 2;   // +6,291,456
    const size_t GI_OFF  = WIH_BF + (size_t)N3H * EMBD * 2;     // +201,326,592
    const size_t H_OFF   = GI_OFF + (size_t)SEQ * BATCH * N3H * 2;
    const size_t FLG_OFF = H_OFF + (size_t)2 * BATCH * HID * 2;
    const size_t NEED    = FLG_OFF + (size_t)NBLK * FLAGSTRIDE * 4;
    if (ws_size < NEED) return;

    char* ws = (char*)d_ws;
    unsigned short* embb = (unsigned short*)(ws + EMB_BF);
    unsigned short* wihb = (unsigned short*)(ws + WIH_BF);
    unsigned short* gib  = (unsigned short*)(ws + GI_OFF);
    unsigned short* hbuf = (unsigned short*)(ws + H_OFF);
    int*            flags = (int*)(ws + FLG_OFF);

    hipMemsetAsync(flags, 0, (size_t)NBLK * FLAGSTRIDE * 4, stream);

    {
        int n4 = VOCAB * EMBD / 4;
        k_cvt4<<<(n4 + 255) / 256, 256, 0, stream>>>((const float4*)emb, (ushort4*)embb, n4);
    }
    {
        int n4 = N3H * EMBD / 4;
        k_cvt4<<<(n4 + 255) / 256, 256, 0, stream>>>((const float4*)W_ih, (ushort4*)wihb, n4);
    }

    // input-side GEMM for all timesteps
    k_gi<<<dim3(48, 128), 256, 0, stream>>>(input, embb, wihb, gib);

    // persistent recurrence: 64 blocks (64 KB LDS each -> all co-resident)
    k_rec<<<NBLK, 256, 0, stream>>>(W_hh, gib, b_ih, b_hh, hidden, out, hbuf, flags);
}